// Round 3
// baseline (55.569 us; speedup 1.0000x reference)
//
#include <hip/hip_runtime.h>
#include <math.h>

#define EPSF 1e-6f
#define NB 4
#define NR 16384
#define NS 48
#define NSEG 47
#define NRAYS (NB * NR)
#define KL 8                  // lanes per ray
#define SPL 6                 // samples per lane
#define RPB 16                // rays per block
#define TPB (RPB * KL)        // 128 threads / block
#define NBLK (NRAYS / RPB)    // 4096 blocks

// LDS region offsets (in floats); layouts are LINEAR images of global memory
#define LC 0                  // colors    16*144 = 2304
#define LS (LC + RPB * 144)   // semantics 16*192 = 3072
#define LD (LS + RPB * 192)   // densities 16*48  = 768
#define LZ (LD + RPB * 48)    // depths    16*48  = 768
#define LW (LZ + RPB * 48)    // weights   16*47 -> 768
#define LTOT (LW + RPB * 48)  // 7680 floats = 30 KiB

typedef const __attribute__((address_space(1))) void as1_cvoid;
typedef __attribute__((address_space(3))) void as3_void;

__device__ __forceinline__ unsigned int f2ord(float f) {
    unsigned int u = __float_as_uint(f);
    return (u & 0x80000000u) ? ~u : (u | 0x80000000u);
}
__device__ __forceinline__ float ord2f(unsigned int v) {
    return __uint_as_float((v & 0x80000000u) ? (v ^ 0x80000000u) : ~v);
}
__device__ __forceinline__ float softplus_f(float x) {
    return fmaxf(x, 0.0f) + log1pf(expf(-fabsf(x)));
}

// coalesced global -> LDS staging: chunk = 1 KiB (64 lanes x 16B), linear layout
__device__ __forceinline__ void stage(const float* g, float* l, int nbytes,
                                      int wid, int lane) {
    const int nchunk = nbytes >> 10;
    for (int i = wid; i < nchunk; i += TPB / 64) {
        __builtin_amdgcn_global_load_lds((as1_cvoid*)(g + i * 256 + lane * 4),
                                         (as3_void*)(l + i * 256), 16, 0, 0);
    }
}

__global__ void init_mm(unsigned int* mm) {
    mm[0] = 0xFFFFFFFFu;
    mm[1] = 0u;
}

__global__ __launch_bounds__(256) void minmax_kernel(const float4* __restrict__ z,
                                                     unsigned int* mm) {
    const int n4 = (NRAYS * NS) / 4;
    float lmin = INFINITY, lmax = -INFINITY;
    for (int i = blockIdx.x * blockDim.x + threadIdx.x; i < n4;
         i += gridDim.x * blockDim.x) {
        float4 v = z[i];
        lmin = fminf(lmin, fminf(fminf(v.x, v.y), fminf(v.z, v.w)));
        lmax = fmaxf(lmax, fmaxf(fmaxf(v.x, v.y), fmaxf(v.z, v.w)));
    }
#pragma unroll
    for (int off = 32; off > 0; off >>= 1) {
        lmin = fminf(lmin, __shfl_down(lmin, off));
        lmax = fmaxf(lmax, __shfl_down(lmax, off));
    }
    __shared__ float smin[4], smax[4];
    int wid = threadIdx.x >> 6;
    if ((threadIdx.x & 63) == 0) { smin[wid] = lmin; smax[wid] = lmax; }
    __syncthreads();
    if (threadIdx.x == 0) {
        float m = fminf(fminf(smin[0], smin[1]), fminf(smin[2], smin[3]));
        float M = fmaxf(fmaxf(smax[0], smax[1]), fmaxf(smax[2], smax[3]));
        atomicMin(&mm[0], f2ord(m));
        atomicMax(&mm[1], f2ord(M));
    }
}

__global__ __launch_bounds__(TPB) void march_kernel(
    const float* __restrict__ colors, const float* __restrict__ densities,
    const float* __restrict__ depths, const float* __restrict__ semantics,
    const int* __restrict__ levels, const unsigned int* __restrict__ mm,
    float* __restrict__ out) {
    __shared__ float lds[LTOT];
    const int tid = threadIdx.x;
    const int lane = tid & 63;
    const int wid = tid >> 6;            // 0..1
    const int ray0 = blockIdx.x * RPB;

    // ---- coalesced staging of this block's contiguous input regions ----
    stage(colors + (size_t)ray0 * 144, lds + LC, RPB * 144 * 4, wid, lane);
    stage(semantics + (size_t)ray0 * 192, lds + LS, RPB * 192 * 4, wid, lane);
    stage(densities + (size_t)ray0 * 48, lds + LD, RPB * 48 * 4, wid, lane);
    stage(depths + (size_t)ray0 * 48, lds + LZ, RPB * 48 * 4, wid, lane);
    __syncthreads();  // drains vmcnt (global_load_lds) before LDS reads

    const int r = tid >> 3;              // local ray 0..15
    const int t = tid & 7;               // lane-in-group, owns samples 6t..6t+5
    const int ray = ray0 + r;
    const int lv = levels[ray >> 14];

    // ---- LDS -> registers: this lane's 7 samples (incl. boundary) ----
    float C0[7], C1[7], C2[7], DN[7], Z[7], S0[7], S1[7], S2[7], S3[7];
    {
        const float* cb = lds + LC + r * 144 + 18 * t;  // 8B aligned
        const float2* p = (const float2*)cb;
        float2 q0 = p[0], q1 = p[1], q2 = p[2], q3 = p[3], q4 = p[4];
        float2 q5 = p[5], q6 = p[6], q7 = p[7], q8 = p[8], q9 = p[9];
        float qa = cb[20];
        C0[0] = q0.x; C1[0] = q0.y; C2[0] = q1.x;
        C0[1] = q1.y; C1[1] = q2.x; C2[1] = q2.y;
        C0[2] = q3.x; C1[2] = q3.y; C2[2] = q4.x;
        C0[3] = q4.y; C1[3] = q5.x; C2[3] = q5.y;
        C0[4] = q6.x; C1[4] = q6.y; C2[4] = q7.x;
        C0[5] = q7.y; C1[5] = q8.x; C2[5] = q8.y;
        C0[6] = q9.x; C1[6] = q9.y; C2[6] = qa;
    }
    {
        const float4* p = (const float4*)(lds + LS + r * 192 + 24 * t);  // 16B aligned
#pragma unroll
        for (int j = 0; j < 7; ++j) {
            float4 u = p[j];
            S0[j] = u.x; S1[j] = u.y; S2[j] = u.z; S3[j] = u.w;
        }
    }
    {
        const float* db = lds + LD + r * 48 + 6 * t;  // 8B aligned
        const float2* p = (const float2*)db;
        float2 a = p[0], b2 = p[1], c = p[2];
        DN[0] = a.x; DN[1] = a.y; DN[2] = b2.x;
        DN[3] = b2.y; DN[4] = c.x; DN[5] = c.y; DN[6] = db[6];
    }
    {
        const float* zb = lds + LZ + r * 48 + 6 * t;
        const float2* p = (const float2*)zb;
        float2 a = p[0], b2 = p[1], c = p[2];
        Z[0] = a.x; Z[1] = a.y; Z[2] = b2.x;
        Z[3] = b2.y; Z[4] = c.x; Z[5] = c.y; Z[6] = zb[6];
    }
    // note: for t==7 the [6] entries read in-LDS garbage; all uses are guarded.

    // ---- local pass: T starts at 1 within this lane's chunk ----
    float T = 1.0f;
    float wl[SPL];
    float acc_r = 0.f, acc_g = 0.f, acc_b = 0.f, acc_d = 0.f;
    float acc_s0 = 0.f, acc_s1 = 0.f, acc_s2 = 0.f, acc_s3 = 0.f;

#pragma unroll
    for (int j = 0; j < SPL; ++j) {
        wl[j] = 0.0f;
        if (j < 5 || t < 7) {  // lane 7 only has 5 segments
            float delta = Z[j + 1] - Z[j];
            float cm0 = (C0[j] + C0[j + 1]) * 0.5f;
            float cm1 = (C1[j] + C1[j + 1]) * 0.5f;
            float cm2 = (C2[j] + C2[j + 1]) * 0.5f;
            float dnm = (DN[j] + DN[j + 1]) * 0.5f;
            float zm  = (Z[j] + Z[j + 1]) * 0.5f;
            float sm0 = (S0[j] + S0[j + 1]) * 0.5f;
            float sm1 = (S1[j] + S1[j + 1]) * 0.5f;
            float sm2 = (S2[j] + S2[j + 1]) * 0.5f;
            float sm3 = (S3[j] + S3[j + 1]) * 0.5f;

            float sp_ = softplus_f(dnm);
            float alpha = 1.0f - expf(-sp_ * delta);

            float factor, o0, o1, o2, o3;
            if (lv == 1) {
                factor = 1.0f - sm0;
                float inv = 1.0f / (sm1 + sm2 + sm3 + EPSF);
                o0 = 0.0f;
                o1 = (sm1 + EPSF) * inv;
                o2 = (sm2 + EPSF) * inv;
                o3 = (sm3 + EPSF) * inv;
            } else if (lv == 2) {
                factor = 1.0f - sm0 - sm3;
                float inv = 1.0f / (sm1 + sm2 + EPSF);
                o0 = 0.0f;
                o1 = (sm1 + EPSF) * inv;
                o2 = (sm2 + EPSF) * inv;
                o3 = 0.0f;
            } else {
                factor = 1.0f;
                o0 = sm0; o1 = sm1; o2 = sm2; o3 = sm3;
            }

            alpha *= factor;
            float w = alpha * T;
            T *= (1.0f - alpha + 1e-10f);
            wl[j] = w;

            acc_r += w * cm0;
            acc_g += w * cm1;
            acc_b += w * cm2;
            acc_d += w * zm;
            acc_s0 += w * o0;
            acc_s1 += w * o1;
            acc_s2 += w * o2;
            acc_s3 += w * o3;
        }
    }

    // ---- inclusive product scan of local transmittance across 8 lanes ----
    float p = T;
#pragma unroll
    for (int off = 1; off < KL; off <<= 1) {
        float u = __shfl_up(p, off, KL);
        if (t >= off) p *= u;
    }
    float Tstart = __shfl_up(p, 1, KL);
    if (t == 0) Tstart = 1.0f;

    acc_r *= Tstart; acc_g *= Tstart; acc_b *= Tstart; acc_d *= Tstart;
    acc_s0 *= Tstart; acc_s1 *= Tstart; acc_s2 *= Tstart; acc_s3 *= Tstart;

    // stage weights into LDS (linear image of global layout)
#pragma unroll
    for (int j = 0; j < SPL; ++j) {
        if (j < 5 || t < 7) lds[LW + r * NSEG + t * SPL + j] = wl[j] * Tstart;
    }

    // ---- reduce 8 partial composites across the group ----
#pragma unroll
    for (int off = KL / 2; off > 0; off >>= 1) {
        acc_r += __shfl_down(acc_r, off, KL);
        acc_g += __shfl_down(acc_g, off, KL);
        acc_b += __shfl_down(acc_b, off, KL);
        acc_d += __shfl_down(acc_d, off, KL);
        acc_s0 += __shfl_down(acc_s0, off, KL);
        acc_s1 += __shfl_down(acc_s1, off, KL);
        acc_s2 += __shfl_down(acc_s2, off, KL);
        acc_s3 += __shfl_down(acc_s3, off, KL);
    }

    if (t == 0) {
        const float dmin = ord2f(mm[0]);
        const float dmax = ord2f(mm[1]);
        if (isnan(acc_d)) acc_d = INFINITY;
        acc_d = fminf(fmaxf(acc_d, dmin), dmax);

        out[ray * 3 + 0] = acc_r;
        out[ray * 3 + 1] = acc_g;
        out[ray * 3 + 2] = acc_b;
        out[NRAYS * 3 + ray] = acc_d;
        out[NRAYS * 4 + ray * 4 + 0] = acc_s0;
        out[NRAYS * 4 + ray * 4 + 1] = acc_s1;
        out[NRAYS * 4 + ray * 4 + 2] = acc_s2;
        out[NRAYS * 4 + ray * 4 + 3] = acc_s3;
    }

    // ---- coalesced float4 write-out of the block's weights ----
    __syncthreads();
    {
        const float4* src = (const float4*)(lds + LW);
        float4* dst = (float4*)(out + (size_t)NRAYS * 8 + (size_t)ray0 * NSEG);
#pragma unroll
        for (int i = tid; i < (RPB * NSEG) / 4; i += TPB) dst[i] = src[i];
    }
}

extern "C" void kernel_launch(void* const* d_in, const int* in_sizes, int n_in,
                              void* d_out, int out_size, void* d_ws, size_t ws_size,
                              hipStream_t stream) {
    const float* colors = (const float*)d_in[0];
    const float* densities = (const float*)d_in[1];
    const float* depths = (const float*)d_in[2];
    const float* semantics = (const float*)d_in[3];
    const int* levels = (const int*)d_in[4];
    float* out = (float*)d_out;
    unsigned int* mm = (unsigned int*)d_ws;

    init_mm<<<1, 1, 0, stream>>>(mm);
    minmax_kernel<<<512, 256, 0, stream>>>((const float4*)depths, mm);
    march_kernel<<<NBLK, TPB, 0, stream>>>(colors, densities, depths, semantics,
                                           levels, mm, out);
}